// Round 9
// baseline (305.924 us; speedup 1.0000x reference)
//
#include <hip/hip_runtime.h>
#include <math.h>

#define NE 8
#define KDIM 4096
#define PDIM 64
#define WROWS (KDIM + PDIM)   // 4160
#define EPS_F32 1.1920929e-07f
#define NCHUNK 16             // 4096 / (64 lanes * 4 floats)
#define TPW 2                 // tokens per wave
#define WAVES 16              // waves per block (1024 threads)
#define ROWF4 (WROWS / 4)     // 1040 f4 per Wt row
#define LDSF4 (NE * ROWF4)    // 8320 f4 = 133120 B of LDS
#define REP 2                 // DIAGNOSTIC: run the x-pass twice to (a) push
                              // topk_gate above the ~78us fill threshold so
                              // rocprof finally shows its counters, and
                              // (b) split HBM-supply vs kernel-internal
                              // limits: pass 2 finds x L3-resident.

typedef float f4 __attribute__((ext_vector_type(4)));

// --- tiny setup kernel: W[4160][8] -> Wt[8][4160] in d_ws ---
__global__ __launch_bounds__(256)
void transpose_w(const float* __restrict__ W, float* __restrict__ Wt) {
    const int k = blockIdx.x * 256 + threadIdx.x;
    if (k < WROWS) {
        float v[NE];
#pragma unroll
        for (int e = 0; e < NE; ++e) v[e] = W[(size_t)k * NE + e];
#pragma unroll
        for (int e = 0; e < NE; ++e) Wt[(size_t)e * WROWS + k] = v[e];
    }
}

// EXACT R5 structure (best known: 202.4 us) + REP=2 measurement loop.
// R5: Wt staged in LDS once per block (133 KB), 16 waves x 2 tokens,
// depth-2 NT x prefetch, block-uniform 16-way phase stagger, grid 256.
// The rep loop re-runs the full compute; an asm memory clobber between
// reps prevents cross-rep CSE (stores are idempotent -> correctness
// unchanged). Pass 1: x from HBM (cold). Pass 2: x from L3 (134 MB fits,
// nothing sweeps L3 mid-kernel). dur ~95-105 => HBM-supply-limited;
// dur ~115-125 => kernel-internal limit. Also first direct read of
// VGPR/WRITE_SIZE (spill check) for the healthy structure.
__global__ __launch_bounds__(1024, 4)
void topk_gate(const float* __restrict__ x,
               const float* __restrict__ prompt,
               const float* __restrict__ Wt,
               const float* __restrict__ b,
               float* __restrict__ out,
               int tokens)
{
    __shared__ f4 wlds[LDSF4];          // 133120 B

    const int tid  = threadIdx.x;
    const int lane = tid & 63;          // 0..63
    const int wid  = tid >> 6;          // 0..15

    // ---- stage Wt -> LDS (linear f4 copy, coalesced, conflict-free) ----
    {
        const f4* wt4 = (const f4*)Wt;
        for (int i = tid; i < LDSF4; i += WAVES * 64)
            wlds[i] = wt4[i];
    }
    __syncthreads();

    const int tbase = (blockIdx.x * WAVES + wid) * TPW;
    const int phase = (blockIdx.x * 5) & 15;

    const f4* xr0 = (const f4*)(x + (size_t)tbase * KDIM);
    const f4* xr1 = (const f4*)(x + (size_t)(tbase + 1) * KDIM);

    auto cidx = [&](int c) { return ((c + phase) & 15) * 64 + lane; };  // f4 units

    for (int rep = 0; rep < REP; ++rep) {
        if (rep) asm volatile("" ::: "memory");   // forbid cross-rep CSE

        float acc[TPW][NE];
#pragma unroll
        for (int t = 0; t < TPW; ++t)
#pragma unroll
            for (int e = 0; e < NE; ++e) acc[t][e] = 0.f;

        f4 xb[3][TPW];     // x: depth-2 prefetch (3 buffers)

        // ---- prologue: x(0), x(1) ----
        {
            const int k0 = cidx(0);
            xb[0][0] = __builtin_nontemporal_load(xr0 + k0);
            xb[0][1] = __builtin_nontemporal_load(xr1 + k0);
            const int k1 = cidx(1);
            xb[1][0] = __builtin_nontemporal_load(xr0 + k1);
            xb[1][1] = __builtin_nontemporal_load(xr1 + k1);
        }

#pragma unroll
        for (int c = 0; c < NCHUNK; ++c) {
            if (c + 2 < NCHUNK) {
                const int kx = cidx(c + 2);
                xb[(c + 2) % 3][0] = __builtin_nontemporal_load(xr0 + kx);
                xb[(c + 2) % 3][1] = __builtin_nontemporal_load(xr1 + kx);
            }

            const int kw = cidx(c);
            f4 wb[NE];
#pragma unroll
            for (int e = 0; e < NE; ++e)
                wb[e] = wlds[e * ROWF4 + kw];

            const int s = c % 3;
#pragma unroll
            for (int t = 0; t < TPW; ++t)
#pragma unroll
                for (int e = 0; e < NE; ++e) {
                    const f4 xv = xb[s][t];
                    acc[t][e] = fmaf(xv.x, wb[e].x, acc[t][e]);
                    acc[t][e] = fmaf(xv.y, wb[e].y, acc[t][e]);
                    acc[t][e] = fmaf(xv.z, wb[e].z, acc[t][e]);
                    acc[t][e] = fmaf(xv.w, wb[e].w, acc[t][e]);
                }
        }

        // prompt part (64 dims): lanes 0..15, w from LDS f4 cols 1024..1039
        if (lane < 16) {
            f4 pv[TPW];
#pragma unroll
            for (int t = 0; t < TPW; ++t)
                pv[t] = *((const f4*)(prompt + (size_t)(tbase + t) * PDIM) + lane);
#pragma unroll
            for (int e = 0; e < NE; ++e) {
                const f4 wv = wlds[e * ROWF4 + (KDIM / 4) + lane];
#pragma unroll
                for (int t = 0; t < TPW; ++t) {
                    acc[t][e] = fmaf(pv[t].x, wv.x, acc[t][e]);
                    acc[t][e] = fmaf(pv[t].y, wv.y, acc[t][e]);
                    acc[t][e] = fmaf(pv[t].z, wv.z, acc[t][e]);
                    acc[t][e] = fmaf(pv[t].w, wv.w, acc[t][e]);
                }
            }
        }

        // butterfly reduce
#pragma unroll
        for (int t = 0; t < TPW; ++t)
#pragma unroll
            for (int e = 0; e < NE; ++e) {
                float v = acc[t][e];
#pragma unroll
                for (int off = 32; off >= 1; off >>= 1)
                    v += __shfl_xor(v, off, 64);
                acc[t][e] = v;
            }

        // ---- epilogue: lanes 0..31, lane = tt*16 + kk*8 + ee ----
        const int tt = (lane >> 4) & 1;
        const int kk = (lane >> 3) & 1;
        const int ee = lane & 7;

        float lg[NE];
#pragma unroll
        for (int e = 0; e < NE; ++e) {
            const float v = (tt == 0) ? acc[0][e] : acc[1][e];
            lg[e] = v + b[e];
        }

        float v0 = lg[0]; int i0 = 0;
#pragma unroll
        for (int e = 1; e < NE; ++e)
            if (lg[e] > v0) { v0 = lg[e]; i0 = e; }
        float v1 = (i0 == 0) ? lg[1] : lg[0];
        int   i1 = (i0 == 0) ? 1 : 0;
#pragma unroll
        for (int e = 0; e < NE; ++e)
            if (e != i0 && lg[e] > v1) { v1 = lg[e]; i1 = e; }

        float s = 0.f;
#pragma unroll
        for (int e = 0; e < NE; ++e) s += __expf(lg[e] - v0);
        const float g0 = 1.0f / s;
        const float g1 = __expf(v1 - v0) / s;
        const float denom = fmaxf(g0 + g1, EPS_F32);

        if (lane < 32) {
            const int sel = kk ? i1 : i0;
            const int t_global = tbase + tt;
            out[(size_t)t_global * 16 + kk * 8 + ee] = (ee == sel) ? 1.0f : 0.0f;

            if ((lane & 15) < 2) {
                const float g = (ee == 0) ? (g0 / denom) : (g1 / denom);
                out[(size_t)tokens * 16 + (size_t)t_global * 2 + ee] = g;
            }
        }
    }
}

extern "C" void kernel_launch(void* const* d_in, const int* in_sizes, int n_in,
                              void* d_out, int out_size, void* d_ws, size_t ws_size,
                              hipStream_t stream) {
    const float* x      = (const float*)d_in[0];
    const float* prompt = (const float*)d_in[1];
    const float* W      = (const float*)d_in[2];
    const float* b      = (const float*)d_in[3];
    float* out          = (float*)d_out;
    float* Wt           = (float*)d_ws;          // 8*4160*4 = 133 KB

    const int tokens = in_sizes[0] / KDIM;       // 8192

    hipLaunchKernelGGL(transpose_w, dim3((WROWS + 255) / 256), dim3(256), 0, stream,
                       W, Wt);
    hipLaunchKernelGGL(topk_gate, dim3(tokens / (WAVES * TPW)), dim3(WAVES * 64),
                       0, stream, x, prompt, Wt, b, out, tokens);
}

// Round 10
// 258.969 us; speedup vs baseline: 1.1813x; 1.1813x over previous
//
#include <hip/hip_runtime.h>
#include <math.h>

#define NE 8
#define KDIM 4096
#define PDIM 64
#define WROWS (KDIM + PDIM)   // 4160
#define EPS_F32 1.1920929e-07f
#define NCHUNK 16             // 4096 / (64 lanes * 4 floats)
#define TPW 2                 // tokens per wave
#define WAVES 16              // waves per block (1024 threads)
#define ROWF4 (WROWS / 4)     // 1040 f4 per Wt row
#define LDSF4 (NE * ROWF4)    // 8320 f4 = 133120 B of LDS

typedef float f4 __attribute__((ext_vector_type(4)));

// --- tiny setup kernel: W[4160][8] -> Wt[8][4160] in d_ws ---
__global__ __launch_bounds__(256)
void transpose_w(const float* __restrict__ W, float* __restrict__ Wt) {
    const int k = blockIdx.x * 256 + threadIdx.x;
    if (k < WROWS) {
        float v[NE];
#pragma unroll
        for (int e = 0; e < NE; ++e) v[e] = W[(size_t)k * NE + e];
#pragma unroll
        for (int e = 0; e < NE; ++e) Wt[(size_t)e * WROWS + k] = v[e];
    }
}

// R5 structure with the SPILL FIXED. R9's REP=2 diagnostic showed the
// "best" R5 kernel wrote 110+ MB of scratch per pass (WRITE_SIZE 222 MB
// at REP=2, VGPR_Count=64 arch + AGPR split): the fully-unrolled 16-step
// chunk loop let the scheduler hoist loads across the whole window and
// liveness blew past the 128-reg/wave hard cap of a 1024-thread block
// (2048 VGPR pool / 16 waves). Fix: bound the scheduling window.
//  - #pragma unroll 4 (NOT full unroll): scheduler can only hoist within
//    a 4-step window; cross-iteration liveness is the 4-buffer xb ring.
//  - xb[4] ring, index c&3, prefetch (c+2)&3: compile-time static within
//    each unrolled instance (rule-#20-safe), depth-2 prefetch preserved.
//  - wb stays transient inside the body (8 ds_read_b128 -> 32 FMAs).
// Demand: xb 32 + wb 32 (transient) + acc 16 + addressing ~15 = ~95-110
// regs <= 128. Everything else identical to R5 (202.4 us best): LDS-
// staged Wt, 16 waves x 2 tokens, NT x loads, 16-way phase stagger.
__global__ __launch_bounds__(1024)
void topk_gate(const float* __restrict__ x,
               const float* __restrict__ prompt,
               const float* __restrict__ Wt,
               const float* __restrict__ b,
               float* __restrict__ out,
               int tokens)
{
    __shared__ f4 wlds[LDSF4];          // 133120 B

    const int tid  = threadIdx.x;
    const int lane = tid & 63;          // 0..63
    const int wid  = tid >> 6;          // 0..15

    // ---- stage Wt -> LDS (linear f4 copy, coalesced, conflict-free) ----
    {
        const f4* wt4 = (const f4*)Wt;
        for (int i = tid; i < LDSF4; i += WAVES * 64)
            wlds[i] = wt4[i];
    }
    __syncthreads();

    const int tbase = (blockIdx.x * WAVES + wid) * TPW;
    const int phase = (blockIdx.x * 5) & 15;

    const f4* xr0 = (const f4*)(x + (size_t)tbase * KDIM);
    const f4* xr1 = (const f4*)(x + (size_t)(tbase + 1) * KDIM);

    auto cidx = [&](int c) { return ((c + phase) & 15) * 64 + lane; };  // f4 units

    float acc[TPW][NE];
#pragma unroll
    for (int t = 0; t < TPW; ++t)
#pragma unroll
        for (int e = 0; e < NE; ++e) acc[t][e] = 0.f;

    f4 xb[4][TPW];     // depth-2 prefetch, period-4 ring (static idx @ unroll 4)

    // ---- prologue: x(0), x(1) ----
    {
        const int k0 = cidx(0);
        xb[0][0] = __builtin_nontemporal_load(xr0 + k0);
        xb[0][1] = __builtin_nontemporal_load(xr1 + k0);
        const int k1 = cidx(1);
        xb[1][0] = __builtin_nontemporal_load(xr0 + k1);
        xb[1][1] = __builtin_nontemporal_load(xr1 + k1);
    }

#pragma unroll 4
    for (int c = 0; c < NCHUNK; ++c) {
        if (c + 2 < NCHUNK) {
            const int kx = cidx(c + 2);
            xb[(c + 2) & 3][0] = __builtin_nontemporal_load(xr0 + kx);
            xb[(c + 2) & 3][1] = __builtin_nontemporal_load(xr1 + kx);
        }

        const int kw = cidx(c);
        f4 wb[NE];
#pragma unroll
        for (int e = 0; e < NE; ++e)
            wb[e] = wlds[e * ROWF4 + kw];

        const int s = c & 3;
#pragma unroll
        for (int t = 0; t < TPW; ++t)
#pragma unroll
            for (int e = 0; e < NE; ++e) {
                const f4 xv = xb[s][t];
                acc[t][e] = fmaf(xv.x, wb[e].x, acc[t][e]);
                acc[t][e] = fmaf(xv.y, wb[e].y, acc[t][e]);
                acc[t][e] = fmaf(xv.z, wb[e].z, acc[t][e]);
                acc[t][e] = fmaf(xv.w, wb[e].w, acc[t][e]);
            }
    }

    // prompt part (64 dims): lanes 0..15, w from LDS f4 cols 1024..1039
    if (lane < 16) {
        f4 pv[TPW];
#pragma unroll
        for (int t = 0; t < TPW; ++t)
            pv[t] = *((const f4*)(prompt + (size_t)(tbase + t) * PDIM) + lane);
#pragma unroll
        for (int e = 0; e < NE; ++e) {
            const f4 wv = wlds[e * ROWF4 + (KDIM / 4) + lane];
#pragma unroll
            for (int t = 0; t < TPW; ++t) {
                acc[t][e] = fmaf(pv[t].x, wv.x, acc[t][e]);
                acc[t][e] = fmaf(pv[t].y, wv.y, acc[t][e]);
                acc[t][e] = fmaf(pv[t].z, wv.z, acc[t][e]);
                acc[t][e] = fmaf(pv[t].w, wv.w, acc[t][e]);
            }
        }
    }

    // butterfly reduce: every lane ends with full logits for both tokens
#pragma unroll
    for (int t = 0; t < TPW; ++t)
#pragma unroll
        for (int e = 0; e < NE; ++e) {
            float v = acc[t][e];
#pragma unroll
            for (int off = 32; off >= 1; off >>= 1)
                v += __shfl_xor(v, off, 64);
            acc[t][e] = v;
        }

    // ---- epilogue: lanes 0..31, lane = tt*16 + kk*8 + ee ----
    const int tt = (lane >> 4) & 1;
    const int kk = (lane >> 3) & 1;
    const int ee = lane & 7;

    float lg[NE];
#pragma unroll
    for (int e = 0; e < NE; ++e) {
        const float v = (tt == 0) ? acc[0][e] : acc[1][e];
        lg[e] = v + b[e];
    }

    // top-2, strict > so smallest index wins ties (jax.lax.top_k semantics)
    float v0 = lg[0]; int i0 = 0;
#pragma unroll
    for (int e = 1; e < NE; ++e)
        if (lg[e] > v0) { v0 = lg[e]; i0 = e; }
    float v1 = (i0 == 0) ? lg[1] : lg[0];
    int   i1 = (i0 == 0) ? 1 : 0;
#pragma unroll
    for (int e = 0; e < NE; ++e)
        if (e != i0 && lg[e] > v1) { v1 = lg[e]; i1 = e; }

    float s = 0.f;
#pragma unroll
    for (int e = 0; e < NE; ++e) s += __expf(lg[e] - v0);
    const float g0 = 1.0f / s;
    const float g1 = __expf(v1 - v0) / s;
    const float denom = fmaxf(g0 + g1, EPS_F32);

    if (lane < 32) {
        const int sel = kk ? i1 : i0;
        const int t_global = tbase + tt;
        out[(size_t)t_global * 16 + kk * 8 + ee] = (ee == sel) ? 1.0f : 0.0f;

        if ((lane & 15) < 2) {
            const float g = (ee == 0) ? (g0 / denom) : (g1 / denom);
            out[(size_t)tokens * 16 + (size_t)t_global * 2 + ee] = g;
        }
    }
}

extern "C" void kernel_launch(void* const* d_in, const int* in_sizes, int n_in,
                              void* d_out, int out_size, void* d_ws, size_t ws_size,
                              hipStream_t stream) {
    const float* x      = (const float*)d_in[0];
    const float* prompt = (const float*)d_in[1];
    const float* W      = (const float*)d_in[2];
    const float* b      = (const float*)d_in[3];
    float* out          = (float*)d_out;
    float* Wt           = (float*)d_ws;          // 8*4160*4 = 133 KB

    const int tokens = in_sizes[0] / KDIM;       // 8192

    hipLaunchKernelGGL(transpose_w, dim3((WROWS + 255) / 256), dim3(256), 0, stream,
                       W, Wt);
    hipLaunchKernelGGL(topk_gate, dim3(tokens / (WAVES * TPW)), dim3(WAVES * 64),
                       0, stream, x, prompt, Wt, b, out, tokens);
}

// Round 11
// 210.667 us; speedup vs baseline: 1.4522x; 1.2293x over previous
//
#include <hip/hip_runtime.h>
#include <math.h>

#define NE 8
#define KDIM 4096
#define PDIM 64
#define WROWS (KDIM + PDIM)   // 4160
#define EPS_F32 1.1920929e-07f
#define NCHUNK 16             // 4096 / (64 lanes * 4 floats)
#define TPW 4                 // tokens per wave
#define WAVES 8               // waves per block (512 threads)
#define ROWF4 (WROWS / 4)     // 1040 f4 per Wt row
#define LDSF4 (NE * ROWF4)    // 8320 f4 = 133120 B of LDS

typedef float f4 __attribute__((ext_vector_type(4)));

// --- tiny setup kernel: W[4160][8] -> Wt[8][4160] in d_ws ---
__global__ __launch_bounds__(256)
void transpose_w(const float* __restrict__ W, float* __restrict__ Wt) {
    const int k = blockIdx.x * 256 + threadIdx.x;
    if (k < WROWS) {
        float v[NE];
#pragma unroll
        for (int e = 0; e < NE; ++e) v[e] = W[(size_t)k * NE + e];
#pragma unroll
        for (int e = 0; e < NE; ++e) Wt[(size_t)e * WROWS + k] = v[e];
    }
}

// SPILL FIX, structural this time. R9/R10 established: a 1024-thread block
// (16 waves/CU) caps at 128 regs/wave (64 arch + 64 AGPR) and this body's
// natural liveness (~150-180: xb ring + scheduler-batched wb ds_reads)
// cannot fit -> 230 MB scratch writes that rival the compulsory x read.
// FETCH was already ideal (167 MB = 134 x + 34 Wt).
// Fix: 512-thread block (8 waves/CU, 1 block/CU via 133 KB LDS) ->
// __launch_bounds__(512,2) gives a 256-reg/wave budget. Demand ~180 regs
// fits with margin; the scheduler may batch freely. R0 (206 us, spill-free)
// proved 2 waves/SIMD hides latency with x AND w in the vm queue; here
// LDS-Wt removes w from the queue entirely, so 2/SIMD is sufficient.
// TPW=4 keeps grid = 8192/32 = 256 = exactly 1 block/CU.
__global__ __launch_bounds__(512, 2)
void topk_gate(const float* __restrict__ x,
               const float* __restrict__ prompt,
               const float* __restrict__ Wt,
               const float* __restrict__ b,
               float* __restrict__ out,
               int tokens)
{
    __shared__ f4 wlds[LDSF4];          // 133120 B

    const int tid  = threadIdx.x;
    const int lane = tid & 63;          // 0..63
    const int wid  = tid >> 6;          // 0..7

    const int tbase = (blockIdx.x * WAVES + wid) * TPW;
    const int phase = (blockIdx.x * 5) & 15;

    const f4* xr[TPW];
#pragma unroll
    for (int t = 0; t < TPW; ++t)
        xr[t] = (const f4*)(x + (size_t)(tbase + t) * KDIM);

    auto cidx = [&](int c) { return ((c + phase) & 15) * 64 + lane; };  // f4 units

    f4 xb[4][TPW];     // depth-2 prefetch ring; indices static under full unroll

    // ---- x prologue FIRST: chunks 0,1 fly while we stage Wt -> LDS ----
    {
        const int k0 = cidx(0);
        const int k1 = cidx(1);
#pragma unroll
        for (int t = 0; t < TPW; ++t) {
            xb[0][t] = __builtin_nontemporal_load(xr[t] + k0);
            xb[1][t] = __builtin_nontemporal_load(xr[t] + k1);
        }
    }

    // ---- stage Wt -> LDS (linear f4 copy, coalesced, conflict-free) ----
    {
        const f4* wt4 = (const f4*)Wt;
        for (int i = tid; i < LDSF4; i += WAVES * 64)
            wlds[i] = wt4[i];
    }
    __syncthreads();

    float acc[TPW][NE];
#pragma unroll
    for (int t = 0; t < TPW; ++t)
#pragma unroll
        for (int e = 0; e < NE; ++e) acc[t][e] = 0.f;

#pragma unroll
    for (int c = 0; c < NCHUNK; ++c) {
        if (c + 2 < NCHUNK) {
            const int kx = cidx(c + 2);
#pragma unroll
            for (int t = 0; t < TPW; ++t)
                xb[(c + 2) & 3][t] = __builtin_nontemporal_load(xr[t] + kx);
        }

        const int kw = cidx(c);
        f4 wb[NE];
#pragma unroll
        for (int e = 0; e < NE; ++e)
            wb[e] = wlds[e * ROWF4 + kw];

        const int s = c & 3;
#pragma unroll
        for (int t = 0; t < TPW; ++t)
#pragma unroll
            for (int e = 0; e < NE; ++e) {
                const f4 xv = xb[s][t];
                acc[t][e] = fmaf(xv.x, wb[e].x, acc[t][e]);
                acc[t][e] = fmaf(xv.y, wb[e].y, acc[t][e]);
                acc[t][e] = fmaf(xv.z, wb[e].z, acc[t][e]);
                acc[t][e] = fmaf(xv.w, wb[e].w, acc[t][e]);
            }
    }

    // prompt part (64 dims): lanes 0..15, w from LDS f4 cols 1024..1039
    if (lane < 16) {
        f4 pv[TPW];
#pragma unroll
        for (int t = 0; t < TPW; ++t)
            pv[t] = *((const f4*)(prompt + (size_t)(tbase + t) * PDIM) + lane);
#pragma unroll
        for (int e = 0; e < NE; ++e) {
            const f4 wv = wlds[e * ROWF4 + (KDIM / 4) + lane];
#pragma unroll
            for (int t = 0; t < TPW; ++t) {
                acc[t][e] = fmaf(pv[t].x, wv.x, acc[t][e]);
                acc[t][e] = fmaf(pv[t].y, wv.y, acc[t][e]);
                acc[t][e] = fmaf(pv[t].z, wv.z, acc[t][e]);
                acc[t][e] = fmaf(pv[t].w, wv.w, acc[t][e]);
            }
        }
    }

    // butterfly reduce: every lane ends with full logits for all 4 tokens
#pragma unroll
    for (int t = 0; t < TPW; ++t)
#pragma unroll
        for (int e = 0; e < NE; ++e) {
            float v = acc[t][e];
#pragma unroll
            for (int off = 32; off >= 1; off >>= 1)
                v += __shfl_xor(v, off, 64);
            acc[t][e] = v;
        }

    // ---- epilogue: lane = tt*16 + kk*8 + ee -> one mask element per lane ----
    const int tt = lane >> 4;
    const int kk = (lane >> 3) & 1;
    const int ee = lane & 7;

    float lg[NE];
#pragma unroll
    for (int e = 0; e < NE; ++e) {
        float v = acc[0][e];
        if (tt == 1) v = acc[1][e];
        if (tt == 2) v = acc[2][e];
        if (tt == 3) v = acc[3][e];
        lg[e] = v + b[e];
    }

    // top-2, strict > so smallest index wins ties (jax.lax.top_k semantics)
    float v0 = lg[0]; int i0 = 0;
#pragma unroll
    for (int e = 1; e < NE; ++e)
        if (lg[e] > v0) { v0 = lg[e]; i0 = e; }
    float v1 = (i0 == 0) ? lg[1] : lg[0];
    int   i1 = (i0 == 0) ? 1 : 0;
#pragma unroll
    for (int e = 0; e < NE; ++e)
        if (e != i0 && lg[e] > v1) { v1 = lg[e]; i1 = e; }

    float s = 0.f;
#pragma unroll
    for (int e = 0; e < NE; ++e) s += __expf(lg[e] - v0);
    const float g0 = 1.0f / s;
    const float g1 = __expf(v1 - v0) / s;
    const float denom = fmaxf(g0 + g1, EPS_F32);

    const int sel = kk ? i1 : i0;
    const int t_global = tbase + tt;
    out[(size_t)t_global * 16 + kk * 8 + ee] = (ee == sel) ? 1.0f : 0.0f;

    if ((lane & 15) < 2) {
        const float g = (ee == 0) ? (g0 / denom) : (g1 / denom);
        out[(size_t)tokens * 16 + (size_t)t_global * 2 + ee] = g;
    }
}

extern "C" void kernel_launch(void* const* d_in, const int* in_sizes, int n_in,
                              void* d_out, int out_size, void* d_ws, size_t ws_size,
                              hipStream_t stream) {
    const float* x      = (const float*)d_in[0];
    const float* prompt = (const float*)d_in[1];
    const float* W      = (const float*)d_in[2];
    const float* b      = (const float*)d_in[3];
    float* out          = (float*)d_out;
    float* Wt           = (float*)d_ws;          // 8*4160*4 = 133 KB

    const int tokens = in_sizes[0] / KDIM;       // 8192

    hipLaunchKernelGGL(transpose_w, dim3((WROWS + 255) / 256), dim3(256), 0, stream,
                       W, Wt);
    hipLaunchKernelGGL(topk_gate, dim3(tokens / (WAVES * TPW)), dim3(WAVES * 64),
                       0, stream, x, prompt, Wt, b, out, tokens);
}